// Round 5
// baseline (3340.546 us; speedup 1.0000x reference)
//
#include <hip/hip_runtime.h>

#define NN   50000
#define NE   800000
#define INCH 8
#define CH   128
#define EA   6
#define NB   2000
#define NCLS 32
#define FUS  384

// ---------- degree of dst nodes ----------
__global__ __launch_bounds__(256) void k_deg(const int* __restrict__ edge,
                                             int* __restrict__ deg) {
  int e = blockIdx.x * 256 + threadIdx.x;
  if (e < NE) atomicAdd(&deg[edge[NE + e]], 1);
}

// ---------- exclusive scan of deg -> row_ptr (single block, shfl scan) ----------
__global__ __launch_bounds__(1024) void k_scan(const int* __restrict__ deg,
                                               int* __restrict__ row_ptr) {
  __shared__ int wsum[16];
  __shared__ int s_carry;
  const int t = threadIdx.x, lane = t & 63, w = t >> 6;
  if (t == 0) s_carry = 0;
  __syncthreads();
  for (int base = 0; base < NN; base += 1024) {
    int i = base + t;
    int x = (i < NN) ? deg[i] : 0;
#pragma unroll
    for (int off = 1; off < 64; off <<= 1) {
      int y = __shfl_up(x, off, 64);
      if (lane >= off) x += y;
    }
    if (lane == 63) wsum[w] = x;
    __syncthreads();
    if (w == 0 && lane < 16) {
      int s = wsum[lane];
#pragma unroll
      for (int off = 1; off < 16; off <<= 1) {
        int y = __shfl_up(s, off, 64);
        if (lane >= off) s += y;
      }
      wsum[lane] = s;
    }
    __syncthreads();
    int incl = x + ((w == 0) ? 0 : wsum[w - 1]) + s_carry;
    if (i < NN) row_ptr[i + 1] = incl;
    __syncthreads();
    if (t == 1023) s_carry = incl;
    __syncthreads();
  }
  if (t == 0) row_ptr[0] = 0;
}

// ---------- fill CSR: edge ids grouped by dst ----------
__global__ __launch_bounds__(256) void k_fill(
    const int* __restrict__ edge, const int* __restrict__ row_ptr,
    int* __restrict__ cursor, int* __restrict__ eid_arr) {
  int e = blockIdx.x * 256 + threadIdx.x;
  if (e >= NE) return;
  int d = edge[NE + e];
  int idx = row_ptr[d] + atomicAdd(&cursor[d], 1);
  eid_arr[idx] = e;
}

// ---------- segment starts from sorted bbox_idx ----------
__global__ __launch_bounds__(256) void k_segstart(const int* __restrict__ bbox,
                                                  int* __restrict__ seg) {
  int i = blockIdx.x * 256 + threadIdx.x;
  if (i >= NN) return;
  int bc = bbox[i];
  int bp = (i == 0) ? -1 : bbox[i - 1];
  for (int j = bp + 1; j <= bc; ++j) seg[j] = i;
  if (i == NN - 1)
    for (int j = bc + 1; j <= NB; ++j) seg[j] = NN;
}

// ---------- node transform: P = X@(W1-W2)+b, Q = X@W2 ----------
template <int NODES>
__global__ __launch_bounds__(128) void k_node_pq(
    const float* __restrict__ X, int ldx, int K,
    const float* __restrict__ W, const float* __restrict__ bias,
    float* __restrict__ P, float* __restrict__ Q) {
  const int oc = threadIdx.x;          // 0..127
  const int n0 = blockIdx.x * NODES;
  float bv = bias[oc];
  float pacc[NODES], qacc[NODES];
#pragma unroll
  for (int u = 0; u < NODES; ++u) { pacc[u] = bv; qacc[u] = 0.f; }
  const float* x0 = X + (size_t)n0 * ldx;
  for (int k = 0; k < K; ++k) {
    float w1 = W[(size_t)k * CH + oc];
    float w2 = W[(size_t)(K + k) * CH + oc];
    float a  = w1 - w2;
#pragma unroll
    for (int u = 0; u < NODES; ++u) {
      float xv = x0[(size_t)u * ldx + k];
      pacc[u] += xv * a;
      qacc[u] += xv * w2;
    }
  }
#pragma unroll
  for (int u = 0; u < NODES; ++u) {
    size_t o = (size_t)(n0 + u) * CH + oc;
    P[o] = pacc[u];
    Q[o] = qacc[u];
  }
}

// ---------- CSR conv: one node per WAVE, lane-batched edge meta + shfl ----------
template <int MODE>  // 0 = max, 1 = mean
__global__ __launch_bounds__(256) void k_conv(
    const int* __restrict__ row_ptr, const int* __restrict__ eid_arr,
    const int* __restrict__ edge, const float* __restrict__ eattr,
    const float* __restrict__ P, const float* __restrict__ Q,
    const float* __restrict__ C, float* __restrict__ outf,
    int cur, int prev) {
  const int t = threadIdx.x;
  const int lane = t & 63;
  const int node = blockIdx.x * 4 + (t >> 6);
  const int c = lane * 2;
  float2 cw[EA];
#pragma unroll
  for (int j = 0; j < EA; ++j) cw[j] = *(const float2*)(C + j * CH + c);
  int i0 = __builtin_amdgcn_readfirstlane(row_ptr[node]);
  int i1 = __builtin_amdgcn_readfirstlane(row_ptr[node + 1]);
  const float2 q = *(const float2*)(Q + (size_t)node * CH + c);
  float a0 = 0.f, a1 = 0.f;
  for (int base = i0; base < i1; base += 64) {
    const int cnt = min(64, i1 - base);
    int s_l = 0;
    float ea0 = 0.f, ea1 = 0.f, ea2 = 0.f, ea3 = 0.f, ea4 = 0.f, ea5 = 0.f;
    if (lane < cnt) {
      int e = eid_arr[base + lane];      // coalesced
      s_l = edge[e];                     // gather
      const float* ep = eattr + (size_t)e * EA;
      ea0 = ep[0]; ea1 = ep[1]; ea2 = ep[2];
      ea3 = ep[3]; ea4 = ep[4]; ea5 = ep[5];
    }
#define EDGE_BODY(J)                                                       \
    {                                                                      \
      int s = __shfl(s_l, (J), 64);                                        \
      float e0 = __shfl(ea0, (J), 64), e1 = __shfl(ea1, (J), 64);          \
      float e2 = __shfl(ea2, (J), 64), e3 = __shfl(ea3, (J), 64);          \
      float e4 = __shfl(ea4, (J), 64), e5 = __shfl(ea5, (J), 64);          \
      const float2 pv = *(const float2*)(P + (size_t)s * CH + c);          \
      float v0 = pv.x + q.x, v1 = pv.y + q.y;                              \
      v0 += e0 * cw[0].x; v1 += e0 * cw[0].y;                              \
      v0 += e1 * cw[1].x; v1 += e1 * cw[1].y;                              \
      v0 += e2 * cw[2].x; v1 += e2 * cw[2].y;                              \
      v0 += e3 * cw[3].x; v1 += e3 * cw[3].y;                              \
      v0 += e4 * cw[4].x; v1 += e4 * cw[4].y;                              \
      v0 += e5 * cw[5].x; v1 += e5 * cw[5].y;                              \
      if (MODE == 0) { a0 = fmaxf(a0, v0); a1 = fmaxf(a1, v1); }           \
      else           { a0 += fmaxf(v0, 0.f); a1 += fmaxf(v1, 0.f); }       \
    }
    int j = 0;
    for (; j + 4 <= cnt; j += 4) {
      EDGE_BODY(j) EDGE_BODY(j + 1) EDGE_BODY(j + 2) EDGE_BODY(j + 3)
    }
    for (; j < cnt; ++j) EDGE_BODY(j)
#undef EDGE_BODY
  }
  if (MODE == 1) {
    float inv = 1.f / fmaxf((float)(i1 - i0), 1.f);
    a0 *= inv; a1 *= inv;
  }
  size_t o = (size_t)node * FUS + (size_t)cur * CH + c;
  if (prev >= 0) {
    const float2 pr = *(const float2*)(outf + (size_t)node * FUS + (size_t)prev * CH + c);
    a0 += pr.x; a1 += pr.y;
  }
  float2 ov = {a0, a1};
  *(float2*)(outf + o) = ov;
}

// ---------- fused fusion-GEMM + bbox pooling, register-blocked ----------
// 256 threads = 2 groups x 128. Group g owns 8 nodes (nb+8g..), thread owns
// 8 cols (c0 = (t&127)*8). No LDS in the hot loop; x via broadcast float4,
// W via coalesced float4. Cross-group max combined once through LDS at end.
__global__ __launch_bounds__(256) void k_pool(
    const float* __restrict__ feats, const float* __restrict__ sfeats,
    const int* __restrict__ seg, const float* __restrict__ Wf,
    const float* __restrict__ bf, float* __restrict__ pooled,
    float* __restrict__ sb) {
  __shared__ float red[128 * 8];       // 4 KB, used once at the end
  const int b = blockIdx.x, t = threadIdx.x;
  const int g = t >> 7, tt = t & 127;
  const int c0 = tt * 8;
  const int n0 = __builtin_amdgcn_readfirstlane(seg[b]);
  const int n1 = __builtin_amdgcn_readfirstlane(seg[b + 1]);
  float mraw[8];
#pragma unroll
  for (int i = 0; i < 8; ++i) mraw[i] = -1e30f;
  float4 fmx = {0.f, 0.f, 0.f, 0.f};
  float4 ss  = {0.f, 0.f, 0.f, 0.f};
  for (int nb = n0; nb < n1; nb += 16) {
    const int base = nb + g * 8;
    float acc[8][8];
#pragma unroll
    for (int u = 0; u < 8; ++u)
#pragma unroll
      for (int i = 0; i < 8; ++i) acc[u][i] = 0.f;
    for (int k = 0; k < FUS; k += 4) {
      float4 xv[8];
#pragma unroll
      for (int u = 0; u < 8; ++u)   // broadcast loads; overread stays in ws
        xv[u] = *(const float4*)(feats + (size_t)(base + u) * FUS + k);
#pragma unroll
      for (int kk = 0; kk < 4; ++kk) {
        const float4 w0 = *(const float4*)(Wf + (size_t)(k + kk) * 1024 + c0);
        const float4 w1 = *(const float4*)(Wf + (size_t)(k + kk) * 1024 + c0 + 4);
#pragma unroll
        for (int u = 0; u < 8; ++u) {
          const float xs = ((const float*)&xv[u])[kk];
          acc[u][0] += xs * w0.x; acc[u][1] += xs * w0.y;
          acc[u][2] += xs * w0.z; acc[u][3] += xs * w0.w;
          acc[u][4] += xs * w1.x; acc[u][5] += xs * w1.y;
          acc[u][6] += xs * w1.z; acc[u][7] += xs * w1.w;
        }
      }
    }
    const int cnt_g = min(8, max(0, n1 - base));
#pragma unroll
    for (int u = 0; u < 8; ++u)
      if (u < cnt_g)
#pragma unroll
        for (int i = 0; i < 8; ++i) mraw[i] = fmaxf(mraw[i], acc[u][i]);
    // raw-feats max + sfeats mean over the 16-node chunk (384 cols, t<96)
    if (t < 96) {
      const int cnt = min(16, n1 - nb);
      for (int u = 0; u < cnt; ++u) {
        const float4 f4 = *(const float4*)(feats + (size_t)(nb + u) * FUS + t * 4);
        fmx.x = fmaxf(fmx.x, f4.x); fmx.y = fmaxf(fmx.y, f4.y);
        fmx.z = fmaxf(fmx.z, f4.z); fmx.w = fmaxf(fmx.w, f4.w);
        const float4 s4 = *(const float4*)(sfeats + (size_t)(nb + u) * FUS + t * 4);
        ss.x += s4.x; ss.y += s4.y; ss.z += s4.z; ss.w += s4.w;
      }
    }
  }
  // cross-group max combine
  if (g == 1) {
#pragma unroll
    for (int i = 0; i < 8; ++i) red[tt * 8 + i] = mraw[i];
  }
  __syncthreads();
  if (g == 0) {
#pragma unroll
    for (int i = 0; i < 8; ++i) mraw[i] = fmaxf(mraw[i], red[tt * 8 + i]);
    float o0[8];
    const bool nonempty = (n1 > n0);
#pragma unroll
    for (int i = 0; i < 8; ++i)
      o0[i] = nonempty ? fmaxf(mraw[i] + bf[c0 + i], 0.f) : 0.f;
    *(float4*)(pooled + (size_t)b * 1408 + c0)     = *(float4*)&o0[0];
    *(float4*)(pooled + (size_t)b * 1408 + c0 + 4) = *(float4*)&o0[4];
  }
  if (t < 96) {
    *(float4*)(pooled + (size_t)b * 1408 + 1024 + t * 4) = fmx;
    float inv = 1.f / fmaxf((float)(n1 - n0), 1.f);
    float4 o = {ss.x * inv, ss.y * inv, ss.z * inv, ss.w * inv};
    *(float4*)(sb + (size_t)b * FUS + t * 4) = o;
  }
}

// ---------- fusion_super = relu(sb @ Wfs + bfs) ----------
__global__ __launch_bounds__(256) void k_fusion_super(
    const float* __restrict__ sb, const float* __restrict__ Wfs,
    const float* __restrict__ bfs, float* __restrict__ fs) {
  const int r0 = blockIdx.x * 8, t = threadIdx.x;
  float acc[8][4];
#pragma unroll
  for (int u = 0; u < 8; ++u)
    acc[u][0] = acc[u][1] = acc[u][2] = acc[u][3] = 0.f;
  for (int k = 0; k < FUS; ++k) {
    const float4 w = *(const float4*)(Wfs + (size_t)k * 1024 + t * 4);
#pragma unroll
    for (int u = 0; u < 8; ++u) {
      float x = sb[(size_t)(r0 + u) * FUS + k];
      acc[u][0] += x * w.x; acc[u][1] += x * w.y;
      acc[u][2] += x * w.z; acc[u][3] += x * w.w;
    }
  }
  const float4 b4 = *(const float4*)(bfs + t * 4);
#pragma unroll
  for (int u = 0; u < 8; ++u) {
    float4 o = {fmaxf(acc[u][0] + b4.x, 0.f), fmaxf(acc[u][1] + b4.y, 0.f),
                fmaxf(acc[u][2] + b4.z, 0.f), fmaxf(acc[u][3] + b4.w, 0.f)};
    *(float4*)(fs + (size_t)(r0 + u) * 1024 + t * 4) = o;
  }
}

// ---------- h1 = relu(concat(pooled, fs, sb) @ W1 + b1), column-split ----------
__global__ __launch_bounds__(256) void k_mlp1(
    const float* __restrict__ pooled, const float* __restrict__ fs,
    const float* __restrict__ sb, const float* __restrict__ W1,
    const float* __restrict__ b1, float* __restrict__ h1) {
  const int r0 = blockIdx.x * 8;
  const int col = blockIdx.y * 256 + threadIdx.x;
  float acc[8];
#pragma unroll
  for (int u = 0; u < 8; ++u) acc[u] = 0.f;
  for (int k = 0; k < 1408; ++k) {
    float w = W1[(size_t)k * 512 + col];
#pragma unroll
    for (int u = 0; u < 8; ++u) acc[u] += pooled[(size_t)(r0 + u) * 1408 + k] * w;
  }
  for (int k = 0; k < 1024; ++k) {
    float w = W1[(size_t)(1408 + k) * 512 + col];
#pragma unroll
    for (int u = 0; u < 8; ++u) acc[u] += fs[(size_t)(r0 + u) * 1024 + k] * w;
  }
  for (int k = 0; k < FUS; ++k) {
    float w = W1[(size_t)(2432 + k) * 512 + col];
#pragma unroll
    for (int u = 0; u < 8; ++u) acc[u] += sb[(size_t)(r0 + u) * FUS + k] * w;
  }
  float bv = b1[col];
#pragma unroll
  for (int u = 0; u < 8; ++u)
    h1[(size_t)(r0 + u) * 512 + col] = fmaxf(acc[u] + bv, 0.f);
}

// ---------- h2 = relu(h1 @ W2 + b2) ----------
__global__ __launch_bounds__(256) void k_mlp2(
    const float* __restrict__ h1, const float* __restrict__ W2,
    const float* __restrict__ b2, float* __restrict__ h2) {
  const int r0 = blockIdx.x * 8, t = threadIdx.x;
  float acc[8];
#pragma unroll
  for (int u = 0; u < 8; ++u) acc[u] = 0.f;
  for (int k = 0; k < 512; ++k) {
    float w = W2[(size_t)k * 256 + t];
#pragma unroll
    for (int u = 0; u < 8; ++u) acc[u] += h1[(size_t)(r0 + u) * 512 + k] * w;
  }
  float bv = b2[t];
#pragma unroll
  for (int u = 0; u < 8; ++u)
    h2[(size_t)(r0 + u) * 256 + t] = fmaxf(acc[u] + bv, 0.f);
}

// ---------- logits = h2 @ W3 + b3 ----------
__global__ __launch_bounds__(256) void k_mlp3(
    const float* __restrict__ h2, const float* __restrict__ W3,
    const float* __restrict__ b3, float* __restrict__ out) {
  const int r0 = blockIdx.x * 8, t = threadIdx.x;
  const int u = t >> 5, oc = t & 31;
  const float* x = h2 + (size_t)(r0 + u) * 256;
  float acc = 0.f;
  for (int k = 0; k < 256; ++k) acc += x[k] * W3[(size_t)k * 32 + oc];
  out[(size_t)(r0 + u) * 32 + oc] = acc + b3[oc];
}

extern "C" void kernel_launch(void* const* d_in, const int* in_sizes, int n_in,
                              void* d_out, int out_size, void* d_ws, size_t ws_size,
                              hipStream_t stream) {
  const float* x     = (const float*)d_in[0];
  const float* eattr = (const float*)d_in[1];
  const float* W_h   = (const float*)d_in[2];
  const float* b_h   = (const float*)d_in[3];
  const float* Ws_h  = (const float*)d_in[4];
  const float* bs_h  = (const float*)d_in[5];
  const float* Wb    = (const float*)d_in[6];
  const float* bb    = (const float*)d_in[7];
  const float* Wbs   = (const float*)d_in[8];
  const float* bbs   = (const float*)d_in[9];
  const float* W_f   = (const float*)d_in[10];
  const float* b_f   = (const float*)d_in[11];
  const float* W_fs  = (const float*)d_in[12];
  const float* b_fs  = (const float*)d_in[13];
  const float* W1    = (const float*)d_in[14];
  const float* b1    = (const float*)d_in[15];
  const float* W2    = (const float*)d_in[16];
  const float* b2    = (const float*)d_in[17];
  const float* W3    = (const float*)d_in[18];
  const float* b3    = (const float*)d_in[19];
  const int*   edge  = (const int*)d_in[20];
  const int*   bbox  = (const int*)d_in[21];
  float* out = (float*)d_out;

  // ---- workspace layout (~209 MB) ----
  float* p = (float*)d_ws;
  float* feats  = p; p += (size_t)NN * FUS;
  float* sfeats = p; p += (size_t)NN * FUS;
  float* P      = p; p += (size_t)NN * CH;
  float* Q      = p; p += (size_t)NN * CH;
  float* sb     = P;                         // overlap: dead after convs
  float* fsup   = P + (size_t)NB * FUS;
  float* h1     = fsup + (size_t)NB * 1024;
  float* h2     = h1 + (size_t)NB * 512;
  float* pooled = Q;
  int* eid_arr = (int*)p;
  int* row_ptr = eid_arr + NE;
  int* deg     = row_ptr + NN + 1;
  int* cursor  = deg + NN;
  int* seg     = cursor + NN;

  hipMemsetAsync(deg, 0, 2 * NN * sizeof(int), stream);  // deg + cursor

  // ---- CSR build + bbox segments ----
  k_deg<<<(NE + 255) / 256, 256, 0, stream>>>(edge, deg);
  k_scan<<<1, 1024, 0, stream>>>(deg, row_ptr);
  k_fill<<<(NE + 255) / 256, 256, 0, stream>>>(edge, row_ptr, cursor, eid_arr);
  k_segstart<<<(NN + 255) / 256, 256, 0, stream>>>(bbox, seg);

  // ---- conv 0 (head): both streams read x (K=8) ----
  k_node_pq<4><<<NN / 4, 128, 0, stream>>>(x, INCH, INCH, W_h, b_h, P, Q);
  k_conv<0><<<NN / 4, 256, 0, stream>>>(row_ptr, eid_arr, edge, eattr, P, Q,
                                        W_h + 2 * INCH * CH, feats, 0, -1);
  k_node_pq<4><<<NN / 4, 128, 0, stream>>>(x, INCH, INCH, Ws_h, bs_h, P, Q);
  k_conv<1><<<NN / 4, 256, 0, stream>>>(row_ptr, eid_arr, edge, eattr, P, Q,
                                        Ws_h + 2 * INCH * CH, sfeats, 0, -1);

  // ---- residual blocks (K=128) ----
  for (int i = 0; i < 2; ++i) {
    const float* Wi  = Wb  + (size_t)i * 262 * CH;
    const float* bi  = bb  + (size_t)i * CH;
    const float* Wsi = Wbs + (size_t)i * 262 * CH;
    const float* bsi = bbs + (size_t)i * CH;
    k_node_pq<16><<<NN / 16, 128, 0, stream>>>(feats + i * CH, FUS, CH, Wi, bi, P, Q);
    k_conv<0><<<NN / 4, 256, 0, stream>>>(row_ptr, eid_arr, edge, eattr, P, Q,
                                          Wi + 2 * CH * CH, feats, i + 1, i);
    k_node_pq<16><<<NN / 16, 128, 0, stream>>>(sfeats + i * CH, FUS, CH, Wsi, bsi, P, Q);
    k_conv<1><<<NN / 4, 256, 0, stream>>>(row_ptr, eid_arr, edge, eattr, P, Q,
                                          Wsi + 2 * CH * CH, sfeats, i + 1, i);
  }

  // ---- pooling + MLP head ----
  k_pool<<<NB, 256, 0, stream>>>(feats, sfeats, seg, W_f, b_f, pooled, sb);
  k_fusion_super<<<NB / 8, 256, 0, stream>>>(sb, W_fs, b_fs, fsup);
  k_mlp1<<<dim3(NB / 8, 2), 256, 0, stream>>>(pooled, fsup, sb, W1, b1, h1);
  k_mlp2<<<NB / 8, 256, 0, stream>>>(h1, W2, b2, h2);
  k_mlp3<<<NB / 8, 256, 0, stream>>>(h2, W3, b3, out);
}

// Round 6
// 2874.735 us; speedup vs baseline: 1.1620x; 1.1620x over previous
//
#include <hip/hip_runtime.h>

#define NN   50000
#define NE   800000
#define INCH 8
#define CH   128
#define EA   6
#define NB   2000
#define NCLS 32
#define FUS  384

// ---------- degree of dst nodes ----------
__global__ __launch_bounds__(256) void k_deg(const int* __restrict__ edge,
                                             int* __restrict__ deg) {
  int e = blockIdx.x * 256 + threadIdx.x;
  if (e < NE) atomicAdd(&deg[edge[NE + e]], 1);
}

// ---------- exclusive scan of deg -> row_ptr (single block, shfl scan) ----------
__global__ __launch_bounds__(1024) void k_scan(const int* __restrict__ deg,
                                               int* __restrict__ row_ptr) {
  __shared__ int wsum[16];
  __shared__ int s_carry;
  const int t = threadIdx.x, lane = t & 63, w = t >> 6;
  if (t == 0) s_carry = 0;
  __syncthreads();
  for (int base = 0; base < NN; base += 1024) {
    int i = base + t;
    int x = (i < NN) ? deg[i] : 0;
#pragma unroll
    for (int off = 1; off < 64; off <<= 1) {
      int y = __shfl_up(x, off, 64);
      if (lane >= off) x += y;
    }
    if (lane == 63) wsum[w] = x;
    __syncthreads();
    if (w == 0 && lane < 16) {
      int s = wsum[lane];
#pragma unroll
      for (int off = 1; off < 16; off <<= 1) {
        int y = __shfl_up(s, off, 64);
        if (lane >= off) s += y;
      }
      wsum[lane] = s;
    }
    __syncthreads();
    int incl = x + ((w == 0) ? 0 : wsum[w - 1]) + s_carry;
    if (i < NN) row_ptr[i + 1] = incl;
    __syncthreads();
    if (t == 1023) s_carry = incl;
    __syncthreads();
  }
  if (t == 0) row_ptr[0] = 0;
}

// ---------- fill CSR: edge ids grouped by dst ----------
__global__ __launch_bounds__(256) void k_fill(
    const int* __restrict__ edge, const int* __restrict__ row_ptr,
    int* __restrict__ cursor, int* __restrict__ eid_arr) {
  int e = blockIdx.x * 256 + threadIdx.x;
  if (e >= NE) return;
  int d = edge[NE + e];
  int idx = row_ptr[d] + atomicAdd(&cursor[d], 1);
  eid_arr[idx] = e;
}

// ---------- segment starts from sorted bbox_idx ----------
__global__ __launch_bounds__(256) void k_segstart(const int* __restrict__ bbox,
                                                  int* __restrict__ seg) {
  int i = blockIdx.x * 256 + threadIdx.x;
  if (i >= NN) return;
  int bc = bbox[i];
  int bp = (i == 0) ? -1 : bbox[i - 1];
  for (int j = bp + 1; j <= bc; ++j) seg[j] = i;
  if (i == NN - 1)
    for (int j = bc + 1; j <= NB; ++j) seg[j] = NN;
}

// ---------- node transform: P = X@(W1-W2)+b, Q = X@W2 ----------
// Block = 4 waves x 8 nodes = 32 nodes. Lane-distributed x: one load covers
// 8 nodes x 8 k (lane>>3 = node, lane&7 = k); consumed via static __shfl
// (v_readlane -> SGPR FMA operand). No wave-uniform loads -> no s_load trap.
// Thread owns cols (2*lane, 2*lane+1) for both P and Q.
__global__ __launch_bounds__(256) void k_node_pq(
    const float* __restrict__ X, int ldx, int K,
    const float* __restrict__ W, const float* __restrict__ bias,
    float* __restrict__ P, float* __restrict__ Q) {
  const int t = threadIdx.x, lane = t & 63, wv = t >> 6;
  const int nbase = blockIdx.x * 32 + wv * 8;
  const int c = lane * 2;
  const float2 bv = *(const float2*)(bias + c);
  float2 pacc[8], qacc[8];
#pragma unroll
  for (int u = 0; u < 8; ++u) { pacc[u] = bv; qacc[u] = make_float2(0.f, 0.f); }
  const int xrow = min(nbase + (lane >> 3), NN - 1);
  const int xk = lane & 7;
  for (int k0 = 0; k0 < K; k0 += 8) {
    const float xv = X[(size_t)xrow * ldx + k0 + xk];
#pragma unroll
    for (int j = 0; j < 8; ++j) {
      const float2 w1 = *(const float2*)(W + (size_t)(k0 + j) * CH + c);
      const float2 w2 = *(const float2*)(W + (size_t)(K + k0 + j) * CH + c);
      const float2 wd = {w1.x - w2.x, w1.y - w2.y};
#pragma unroll
      for (int u = 0; u < 8; ++u) {
        const float xs = __shfl(xv, u * 8 + j, 64);
        pacc[u].x += xs * wd.x; pacc[u].y += xs * wd.y;
        qacc[u].x += xs * w2.x; qacc[u].y += xs * w2.y;
      }
    }
  }
#pragma unroll
  for (int u = 0; u < 8; ++u) {
    const int node = nbase + u;
    if (node < NN) {
      *(float2*)(P + (size_t)node * CH + c) = pacc[u];
      *(float2*)(Q + (size_t)node * CH + c) = qacc[u];
    }
  }
}

// ---------- CSR conv: one node per WAVE, lane-batched edge meta + shfl ----------
template <int MODE>  // 0 = max, 1 = mean
__global__ __launch_bounds__(256) void k_conv(
    const int* __restrict__ row_ptr, const int* __restrict__ eid_arr,
    const int* __restrict__ edge, const float* __restrict__ eattr,
    const float* __restrict__ P, const float* __restrict__ Q,
    const float* __restrict__ C, float* __restrict__ outf,
    int cur, int prev) {
  const int t = threadIdx.x;
  const int lane = t & 63;
  const int node = blockIdx.x * 4 + (t >> 6);
  const int c = lane * 2;
  float2 cw[EA];
#pragma unroll
  for (int j = 0; j < EA; ++j) cw[j] = *(const float2*)(C + j * CH + c);
  int i0 = __builtin_amdgcn_readfirstlane(row_ptr[node]);
  int i1 = __builtin_amdgcn_readfirstlane(row_ptr[node + 1]);
  const float2 q = *(const float2*)(Q + (size_t)node * CH + c);
  float a0 = 0.f, a1 = 0.f;
  for (int base = i0; base < i1; base += 64) {
    const int cnt = min(64, i1 - base);
    int s_l = 0;
    float ea0 = 0.f, ea1 = 0.f, ea2 = 0.f, ea3 = 0.f, ea4 = 0.f, ea5 = 0.f;
    if (lane < cnt) {
      int e = eid_arr[base + lane];      // coalesced
      s_l = edge[e];                     // gather
      const float* ep = eattr + (size_t)e * EA;
      ea0 = ep[0]; ea1 = ep[1]; ea2 = ep[2];
      ea3 = ep[3]; ea4 = ep[4]; ea5 = ep[5];
    }
#define EDGE_BODY(J)                                                       \
    {                                                                      \
      int s = __shfl(s_l, (J), 64);                                        \
      float e0 = __shfl(ea0, (J), 64), e1 = __shfl(ea1, (J), 64);          \
      float e2 = __shfl(ea2, (J), 64), e3 = __shfl(ea3, (J), 64);          \
      float e4 = __shfl(ea4, (J), 64), e5 = __shfl(ea5, (J), 64);          \
      const float2 pv = *(const float2*)(P + (size_t)s * CH + c);          \
      float v0 = pv.x + q.x, v1 = pv.y + q.y;                              \
      v0 += e0 * cw[0].x; v1 += e0 * cw[0].y;                              \
      v0 += e1 * cw[1].x; v1 += e1 * cw[1].y;                              \
      v0 += e2 * cw[2].x; v1 += e2 * cw[2].y;                              \
      v0 += e3 * cw[3].x; v1 += e3 * cw[3].y;                              \
      v0 += e4 * cw[4].x; v1 += e4 * cw[4].y;                              \
      v0 += e5 * cw[5].x; v1 += e5 * cw[5].y;                              \
      if (MODE == 0) { a0 = fmaxf(a0, v0); a1 = fmaxf(a1, v1); }           \
      else           { a0 += fmaxf(v0, 0.f); a1 += fmaxf(v1, 0.f); }       \
    }
    int j = 0;
    for (; j + 4 <= cnt; j += 4) {
      EDGE_BODY(j) EDGE_BODY(j + 1) EDGE_BODY(j + 2) EDGE_BODY(j + 3)
    }
    for (; j < cnt; ++j) EDGE_BODY(j)
#undef EDGE_BODY
  }
  if (MODE == 1) {
    float inv = 1.f / fmaxf((float)(i1 - i0), 1.f);
    a0 *= inv; a1 *= inv;
  }
  size_t o = (size_t)node * FUS + (size_t)cur * CH + c;
  if (prev >= 0) {
    const float2 pr = *(const float2*)(outf + (size_t)node * FUS + (size_t)prev * CH + c);
    a0 += pr.x; a1 += pr.y;
  }
  float2 ov = {a0, a1};
  *(float2*)(outf + o) = ov;
}

// ---------- fused fusion-GEMM + bbox max-pool (GEMM part only) ----------
// 4 waves: half = wv>>1 picks cols (0-511 / 512-1023), wodd = wv&1 picks the
// 8-node subgroup of a 16-node chunk. x via one lane-distributed load
// (8 nodes x 8 k) + static shfl; thread owns 8 cols. Cross-subgroup max via
// 4KB LDS at the end. pooled[b][0:1024] = relu(max + bias); empty bbox -> 0.
__global__ __launch_bounds__(256) void k_pool(
    const float* __restrict__ feats, const int* __restrict__ seg,
    const float* __restrict__ Wf, const float* __restrict__ bf,
    float* __restrict__ pooled) {
  __shared__ float red[1024];
  const int b = blockIdx.x, t = threadIdx.x;
  const int lane = t & 63, wv = t >> 6;
  const int half = wv >> 1, wodd = wv & 1;
  const int col = half * 512 + lane * 8;
  const int n0 = __builtin_amdgcn_readfirstlane(seg[b]);
  const int n1 = __builtin_amdgcn_readfirstlane(seg[b + 1]);
  float mraw[8];
#pragma unroll
  for (int i = 0; i < 8; ++i) mraw[i] = -1e30f;
  const int nsub = lane >> 3, xk = lane & 7;
  for (int nb = n0; nb < n1; nb += 16) {
    const int base = nb + wodd * 8;
    float acc[8][8];
#pragma unroll
    for (int u = 0; u < 8; ++u)
#pragma unroll
      for (int i = 0; i < 8; ++i) acc[u][i] = 0.f;
    const int xrow = min(base + nsub, NN - 1);
    for (int k0 = 0; k0 < FUS; k0 += 8) {
      const float xv = feats[(size_t)xrow * FUS + k0 + xk];
#pragma unroll
      for (int j = 0; j < 8; ++j) {
        const float4 w0 = *(const float4*)(Wf + (size_t)(k0 + j) * 1024 + col);
        const float4 w1 = *(const float4*)(Wf + (size_t)(k0 + j) * 1024 + col + 4);
#pragma unroll
        for (int u = 0; u < 8; ++u) {
          const float xs = __shfl(xv, u * 8 + j, 64);
          acc[u][0] += xs * w0.x; acc[u][1] += xs * w0.y;
          acc[u][2] += xs * w0.z; acc[u][3] += xs * w0.w;
          acc[u][4] += xs * w1.x; acc[u][5] += xs * w1.y;
          acc[u][6] += xs * w1.z; acc[u][7] += xs * w1.w;
        }
      }
    }
    const int cnt = min(8, max(0, n1 - base));
#pragma unroll
    for (int u = 0; u < 8; ++u)
      if (u < cnt)
#pragma unroll
        for (int i = 0; i < 8; ++i) mraw[i] = fmaxf(mraw[i], acc[u][i]);
  }
  if (wodd == 1) {
#pragma unroll
    for (int i = 0; i < 8; ++i) red[col + i] = mraw[i];
  }
  __syncthreads();
  if (wodd == 0) {
    const bool nonempty = (n1 > n0);
    float o[8];
#pragma unroll
    for (int i = 0; i < 8; ++i) {
      float m = fmaxf(mraw[i], red[col + i]);
      o[i] = nonempty ? fmaxf(m + bf[col + i], 0.f) : 0.f;
    }
    *(float4*)(pooled + (size_t)b * 1408 + col)     = *(float4*)&o[0];
    *(float4*)(pooled + (size_t)b * 1408 + col + 4) = *(float4*)&o[4];
  }
}

// ---------- raw-feats bbox max + sfeats bbox mean ----------
// pooled[b][1024:1408] = max feats; sb[b][0:384] = mean sfeats
__global__ __launch_bounds__(256) void k_poolraw(
    const float* __restrict__ feats, const float* __restrict__ sfeats,
    const int* __restrict__ seg, float* __restrict__ pooled,
    float* __restrict__ sb) {
  const int b = blockIdx.x, t = threadIdx.x;
  if (t >= 192) return;
  const int c2 = t * 2;
  const int n0 = __builtin_amdgcn_readfirstlane(seg[b]);
  const int n1 = __builtin_amdgcn_readfirstlane(seg[b + 1]);
  float2 fmx = {0.f, 0.f}, ss = {0.f, 0.f};
  for (int n = n0; n < n1; ++n) {
    const float2 f2 = *(const float2*)(feats + (size_t)n * FUS + c2);
    fmx.x = fmaxf(fmx.x, f2.x); fmx.y = fmaxf(fmx.y, f2.y);
    const float2 s2 = *(const float2*)(sfeats + (size_t)n * FUS + c2);
    ss.x += s2.x; ss.y += s2.y;
  }
  *(float2*)(pooled + (size_t)b * 1408 + 1024 + c2) = fmx;
  const float inv = 1.f / fmaxf((float)(n1 - n0), 1.f);
  float2 o = {ss.x * inv, ss.y * inv};
  *(float2*)(sb + (size_t)b * FUS + c2) = o;
}

// ---------- fusion_super = relu(sb @ Wfs + bfs) ----------
__global__ __launch_bounds__(256) void k_fusion_super(
    const float* __restrict__ sb, const float* __restrict__ Wfs,
    const float* __restrict__ bfs, float* __restrict__ fs) {
  const int r0 = blockIdx.x * 8, t = threadIdx.x;
  float acc[8][4];
#pragma unroll
  for (int u = 0; u < 8; ++u)
    acc[u][0] = acc[u][1] = acc[u][2] = acc[u][3] = 0.f;
  for (int k = 0; k < FUS; ++k) {
    const float4 w = *(const float4*)(Wfs + (size_t)k * 1024 + t * 4);
#pragma unroll
    for (int u = 0; u < 8; ++u) {
      float x = sb[(size_t)(r0 + u) * FUS + k];
      acc[u][0] += x * w.x; acc[u][1] += x * w.y;
      acc[u][2] += x * w.z; acc[u][3] += x * w.w;
    }
  }
  const float4 b4 = *(const float4*)(bfs + t * 4);
#pragma unroll
  for (int u = 0; u < 8; ++u) {
    float4 o = {fmaxf(acc[u][0] + b4.x, 0.f), fmaxf(acc[u][1] + b4.y, 0.f),
                fmaxf(acc[u][2] + b4.z, 0.f), fmaxf(acc[u][3] + b4.w, 0.f)};
    *(float4*)(fs + (size_t)(r0 + u) * 1024 + t * 4) = o;
  }
}

// ---------- h1 = relu(concat(pooled, fs, sb) @ W1 + b1), column-split ----------
__global__ __launch_bounds__(256) void k_mlp1(
    const float* __restrict__ pooled, const float* __restrict__ fs,
    const float* __restrict__ sb, const float* __restrict__ W1,
    const float* __restrict__ b1, float* __restrict__ h1) {
  const int r0 = blockIdx.x * 8;
  const int col = blockIdx.y * 256 + threadIdx.x;
  float acc[8];
#pragma unroll
  for (int u = 0; u < 8; ++u) acc[u] = 0.f;
  for (int k = 0; k < 1408; ++k) {
    float w = W1[(size_t)k * 512 + col];
#pragma unroll
    for (int u = 0; u < 8; ++u) acc[u] += pooled[(size_t)(r0 + u) * 1408 + k] * w;
  }
  for (int k = 0; k < 1024; ++k) {
    float w = W1[(size_t)(1408 + k) * 512 + col];
#pragma unroll
    for (int u = 0; u < 8; ++u) acc[u] += fs[(size_t)(r0 + u) * 1024 + k] * w;
  }
  for (int k = 0; k < FUS; ++k) {
    float w = W1[(size_t)(2432 + k) * 512 + col];
#pragma unroll
    for (int u = 0; u < 8; ++u) acc[u] += sb[(size_t)(r0 + u) * FUS + k] * w;
  }
  float bv = b1[col];
#pragma unroll
  for (int u = 0; u < 8; ++u)
    h1[(size_t)(r0 + u) * 512 + col] = fmaxf(acc[u] + bv, 0.f);
}

// ---------- h2 = relu(h1 @ W2 + b2) ----------
__global__ __launch_bounds__(256) void k_mlp2(
    const float* __restrict__ h1, const float* __restrict__ W2,
    const float* __restrict__ b2, float* __restrict__ h2) {
  const int r0 = blockIdx.x * 8, t = threadIdx.x;
  float acc[8];
#pragma unroll
  for (int u = 0; u < 8; ++u) acc[u] = 0.f;
  for (int k = 0; k < 512; ++k) {
    float w = W2[(size_t)k * 256 + t];
#pragma unroll
    for (int u = 0; u < 8; ++u) acc[u] += h1[(size_t)(r0 + u) * 512 + k] * w;
  }
  float bv = b2[t];
#pragma unroll
  for (int u = 0; u < 8; ++u)
    h2[(size_t)(r0 + u) * 256 + t] = fmaxf(acc[u] + bv, 0.f);
}

// ---------- logits = h2 @ W3 + b3 ----------
__global__ __launch_bounds__(256) void k_mlp3(
    const float* __restrict__ h2, const float* __restrict__ W3,
    const float* __restrict__ b3, float* __restrict__ out) {
  const int r0 = blockIdx.x * 8, t = threadIdx.x;
  const int u = t >> 5, oc = t & 31;
  const float* x = h2 + (size_t)(r0 + u) * 256;
  float acc = 0.f;
  for (int k = 0; k < 256; ++k) acc += x[k] * W3[(size_t)k * 32 + oc];
  out[(size_t)(r0 + u) * 32 + oc] = acc + b3[oc];
}

extern "C" void kernel_launch(void* const* d_in, const int* in_sizes, int n_in,
                              void* d_out, int out_size, void* d_ws, size_t ws_size,
                              hipStream_t stream) {
  const float* x     = (const float*)d_in[0];
  const float* eattr = (const float*)d_in[1];
  const float* W_h   = (const float*)d_in[2];
  const float* b_h   = (const float*)d_in[3];
  const float* Ws_h  = (const float*)d_in[4];
  const float* bs_h  = (const float*)d_in[5];
  const float* Wb    = (const float*)d_in[6];
  const float* bb    = (const float*)d_in[7];
  const float* Wbs   = (const float*)d_in[8];
  const float* bbs   = (const float*)d_in[9];
  const float* W_f   = (const float*)d_in[10];
  const float* b_f   = (const float*)d_in[11];
  const float* W_fs  = (const float*)d_in[12];
  const float* b_fs  = (const float*)d_in[13];
  const float* W1    = (const float*)d_in[14];
  const float* b1    = (const float*)d_in[15];
  const float* W2    = (const float*)d_in[16];
  const float* b2    = (const float*)d_in[17];
  const float* W3    = (const float*)d_in[18];
  const float* b3    = (const float*)d_in[19];
  const int*   edge  = (const int*)d_in[20];
  const int*   bbox  = (const int*)d_in[21];
  float* out = (float*)d_out;

  // ---- workspace layout (~209 MB) ----
  float* p = (float*)d_ws;
  float* feats  = p; p += (size_t)NN * FUS;
  float* sfeats = p; p += (size_t)NN * FUS;
  float* P      = p; p += (size_t)NN * CH;
  float* Q      = p; p += (size_t)NN * CH;
  float* sb     = P;                         // overlap: dead after convs
  float* fsup   = P + (size_t)NB * FUS;
  float* h1     = fsup + (size_t)NB * 1024;
  float* h2     = h1 + (size_t)NB * 512;
  float* pooled = Q;
  int* eid_arr = (int*)p;
  int* row_ptr = eid_arr + NE;
  int* deg     = row_ptr + NN + 1;
  int* cursor  = deg + NN;
  int* seg     = cursor + NN;

  hipMemsetAsync(deg, 0, 2 * NN * sizeof(int), stream);  // deg + cursor

  // ---- CSR build + bbox segments ----
  k_deg<<<(NE + 255) / 256, 256, 0, stream>>>(edge, deg);
  k_scan<<<1, 1024, 0, stream>>>(deg, row_ptr);
  k_fill<<<(NE + 255) / 256, 256, 0, stream>>>(edge, row_ptr, cursor, eid_arr);
  k_segstart<<<(NN + 255) / 256, 256, 0, stream>>>(bbox, seg);

  const int npq_grid = (NN + 31) / 32;

  // ---- conv 0 (head): both streams read x (K=8) ----
  k_node_pq<<<npq_grid, 256, 0, stream>>>(x, INCH, INCH, W_h, b_h, P, Q);
  k_conv<0><<<NN / 4, 256, 0, stream>>>(row_ptr, eid_arr, edge, eattr, P, Q,
                                        W_h + 2 * INCH * CH, feats, 0, -1);
  k_node_pq<<<npq_grid, 256, 0, stream>>>(x, INCH, INCH, Ws_h, bs_h, P, Q);
  k_conv<1><<<NN / 4, 256, 0, stream>>>(row_ptr, eid_arr, edge, eattr, P, Q,
                                        Ws_h + 2 * INCH * CH, sfeats, 0, -1);

  // ---- residual blocks (K=128) ----
  for (int i = 0; i < 2; ++i) {
    const float* Wi  = Wb  + (size_t)i * 262 * CH;
    const float* bi  = bb  + (size_t)i * CH;
    const float* Wsi = Wbs + (size_t)i * 262 * CH;
    const float* bsi = bbs + (size_t)i * CH;
    k_node_pq<<<npq_grid, 256, 0, stream>>>(feats + i * CH, FUS, CH, Wi, bi, P, Q);
    k_conv<0><<<NN / 4, 256, 0, stream>>>(row_ptr, eid_arr, edge, eattr, P, Q,
                                          Wi + 2 * CH * CH, feats, i + 1, i);
    k_node_pq<<<npq_grid, 256, 0, stream>>>(sfeats + i * CH, FUS, CH, Wsi, bsi, P, Q);
    k_conv<1><<<NN / 4, 256, 0, stream>>>(row_ptr, eid_arr, edge, eattr, P, Q,
                                          Wsi + 2 * CH * CH, sfeats, i + 1, i);
  }

  // ---- pooling + MLP head ----
  k_pool<<<NB, 256, 0, stream>>>(feats, seg, W_f, b_f, pooled);
  k_poolraw<<<NB, 256, 0, stream>>>(feats, sfeats, seg, pooled, sb);
  k_fusion_super<<<NB / 8, 256, 0, stream>>>(sb, W_fs, b_fs, fsup);
  k_mlp1<<<dim3(NB / 8, 2), 256, 0, stream>>>(pooled, fsup, sb, W1, b1, h1);
  k_mlp2<<<NB / 8, 256, 0, stream>>>(h1, W2, b2, h2);
  k_mlp3<<<NB / 8, 256, 0, stream>>>(h2, W3, b3, out);
}

// Round 7
// 2566.903 us; speedup vs baseline: 1.3014x; 1.1199x over previous
//
#include <hip/hip_runtime.h>

#define NN   50000
#define NE   800000
#define INCH 8
#define CH   128
#define EA   6
#define NB   2000
#define NCLS 32
#define FUS  384

// ---------- degree of dst nodes ----------
__global__ __launch_bounds__(256) void k_deg(const int* __restrict__ edge,
                                             int* __restrict__ deg) {
  int e = blockIdx.x * 256 + threadIdx.x;
  if (e < NE) atomicAdd(&deg[edge[NE + e]], 1);
}

// ---------- exclusive scan of deg -> row_ptr (single block, shfl scan) ----------
__global__ __launch_bounds__(1024) void k_scan(const int* __restrict__ deg,
                                               int* __restrict__ row_ptr) {
  __shared__ int wsum[16];
  __shared__ int s_carry;
  const int t = threadIdx.x, lane = t & 63, w = t >> 6;
  if (t == 0) s_carry = 0;
  __syncthreads();
  for (int base = 0; base < NN; base += 1024) {
    int i = base + t;
    int x = (i < NN) ? deg[i] : 0;
#pragma unroll
    for (int off = 1; off < 64; off <<= 1) {
      int y = __shfl_up(x, off, 64);
      if (lane >= off) x += y;
    }
    if (lane == 63) wsum[w] = x;
    __syncthreads();
    if (w == 0 && lane < 16) {
      int s = wsum[lane];
#pragma unroll
      for (int off = 1; off < 16; off <<= 1) {
        int y = __shfl_up(s, off, 64);
        if (lane >= off) s += y;
      }
      wsum[lane] = s;
    }
    __syncthreads();
    int incl = x + ((w == 0) ? 0 : wsum[w - 1]) + s_carry;
    if (i < NN) row_ptr[i + 1] = incl;
    __syncthreads();
    if (t == 1023) s_carry = incl;
    __syncthreads();
  }
  if (t == 0) row_ptr[0] = 0;
}

// ---------- fill CSR: edge ids grouped by dst ----------
__global__ __launch_bounds__(256) void k_fill(
    const int* __restrict__ edge, const int* __restrict__ row_ptr,
    int* __restrict__ cursor, int* __restrict__ eid_arr) {
  int e = blockIdx.x * 256 + threadIdx.x;
  if (e >= NE) return;
  int d = edge[NE + e];
  int idx = row_ptr[d] + atomicAdd(&cursor[d], 1);
  eid_arr[idx] = e;
}

// ---------- segment starts from sorted bbox_idx ----------
__global__ __launch_bounds__(256) void k_segstart(const int* __restrict__ bbox,
                                                  int* __restrict__ seg) {
  int i = blockIdx.x * 256 + threadIdx.x;
  if (i >= NN) return;
  int bc = bbox[i];
  int bp = (i == 0) ? -1 : bbox[i - 1];
  for (int j = bp + 1; j <= bc; ++j) seg[j] = i;
  if (i == NN - 1)
    for (int j = bc + 1; j <= NB; ++j) seg[j] = NN;
}

// ---------- node transform: P = X@(W1-W2)+b, Q = X@W2 ----------
// Block = 4 waves x 8 nodes. Lane-distributed x (8 nodes x 8 k per load),
// consumed via static __shfl (v_readlane -> SGPR FMA operand).
__global__ __launch_bounds__(256) void k_node_pq(
    const float* __restrict__ X, int ldx, int K,
    const float* __restrict__ W, const float* __restrict__ bias,
    float* __restrict__ P, float* __restrict__ Q) {
  const int t = threadIdx.x, lane = t & 63, wv = t >> 6;
  const int nbase = blockIdx.x * 32 + wv * 8;
  const int c = lane * 2;
  const float2 bv = *(const float2*)(bias + c);
  float2 pacc[8], qacc[8];
#pragma unroll
  for (int u = 0; u < 8; ++u) { pacc[u] = bv; qacc[u] = make_float2(0.f, 0.f); }
  const int xrow = min(nbase + (lane >> 3), NN - 1);
  const int xk = lane & 7;
  for (int k0 = 0; k0 < K; k0 += 8) {
    const float xv = X[(size_t)xrow * ldx + k0 + xk];
#pragma unroll
    for (int j = 0; j < 8; ++j) {
      const float2 w1 = *(const float2*)(W + (size_t)(k0 + j) * CH + c);
      const float2 w2 = *(const float2*)(W + (size_t)(K + k0 + j) * CH + c);
      const float2 wd = {w1.x - w2.x, w1.y - w2.y};
#pragma unroll
      for (int u = 0; u < 8; ++u) {
        const float xs = __shfl(xv, u * 8 + j, 64);
        pacc[u].x += xs * wd.x; pacc[u].y += xs * wd.y;
        qacc[u].x += xs * w2.x; qacc[u].y += xs * w2.y;
      }
    }
  }
#pragma unroll
  for (int u = 0; u < 8; ++u) {
    const int node = nbase + u;
    if (node < NN) {
      *(float2*)(P + (size_t)node * CH + c) = pacc[u];
      *(float2*)(Q + (size_t)node * CH + c) = qacc[u];
    }
  }
}

// ---------- CSR conv: one node per WAVE, lane-batched edge meta + shfl ----------
template <int MODE>  // 0 = max, 1 = mean
__global__ __launch_bounds__(256) void k_conv(
    const int* __restrict__ row_ptr, const int* __restrict__ eid_arr,
    const int* __restrict__ edge, const float* __restrict__ eattr,
    const float* __restrict__ P, const float* __restrict__ Q,
    const float* __restrict__ C, float* __restrict__ outf,
    int cur, int prev) {
  const int t = threadIdx.x;
  const int lane = t & 63;
  const int node = blockIdx.x * 4 + (t >> 6);
  const int c = lane * 2;
  float2 cw[EA];
#pragma unroll
  for (int j = 0; j < EA; ++j) cw[j] = *(const float2*)(C + j * CH + c);
  int i0 = __builtin_amdgcn_readfirstlane(row_ptr[node]);
  int i1 = __builtin_amdgcn_readfirstlane(row_ptr[node + 1]);
  const float2 q = *(const float2*)(Q + (size_t)node * CH + c);
  float a0 = 0.f, a1 = 0.f;
  for (int base = i0; base < i1; base += 64) {
    const int cnt = min(64, i1 - base);
    int s_l = 0;
    float ea0 = 0.f, ea1 = 0.f, ea2 = 0.f, ea3 = 0.f, ea4 = 0.f, ea5 = 0.f;
    if (lane < cnt) {
      int e = eid_arr[base + lane];      // coalesced
      s_l = edge[e];                     // gather
      const float* ep = eattr + (size_t)e * EA;
      ea0 = ep[0]; ea1 = ep[1]; ea2 = ep[2];
      ea3 = ep[3]; ea4 = ep[4]; ea5 = ep[5];
    }
#define EDGE_BODY(J)                                                       \
    {                                                                      \
      int s = __shfl(s_l, (J), 64);                                        \
      float e0 = __shfl(ea0, (J), 64), e1 = __shfl(ea1, (J), 64);          \
      float e2 = __shfl(ea2, (J), 64), e3 = __shfl(ea3, (J), 64);          \
      float e4 = __shfl(ea4, (J), 64), e5 = __shfl(ea5, (J), 64);          \
      const float2 pv = *(const float2*)(P + (size_t)s * CH + c);          \
      float v0 = pv.x + q.x, v1 = pv.y + q.y;                              \
      v0 += e0 * cw[0].x; v1 += e0 * cw[0].y;                              \
      v0 += e1 * cw[1].x; v1 += e1 * cw[1].y;                              \
      v0 += e2 * cw[2].x; v1 += e2 * cw[2].y;                              \
      v0 += e3 * cw[3].x; v1 += e3 * cw[3].y;                              \
      v0 += e4 * cw[4].x; v1 += e4 * cw[4].y;                              \
      v0 += e5 * cw[5].x; v1 += e5 * cw[5].y;                              \
      if (MODE == 0) { a0 = fmaxf(a0, v0); a1 = fmaxf(a1, v1); }           \
      else           { a0 += fmaxf(v0, 0.f); a1 += fmaxf(v1, 0.f); }       \
    }
    int j = 0;
    for (; j + 4 <= cnt; j += 4) {
      EDGE_BODY(j) EDGE_BODY(j + 1) EDGE_BODY(j + 2) EDGE_BODY(j + 3)
    }
    for (; j < cnt; ++j) EDGE_BODY(j)
#undef EDGE_BODY
  }
  if (MODE == 1) {
    float inv = 1.f / fmaxf((float)(i1 - i0), 1.f);
    a0 *= inv; a1 *= inv;
  }
  size_t o = (size_t)node * FUS + (size_t)cur * CH + c;
  if (prev >= 0) {
    const float2 pr = *(const float2*)(outf + (size_t)node * FUS + (size_t)prev * CH + c);
    a0 += pr.x; a1 += pr.y;
  }
  float2 ov = {a0, a1};
  *(float2*)(outf + o) = ov;
}

// ---------- fusion GEMM over ALL nodes + segment max via atomicMax ----------
// Dense tiles: 32 nodes x 512 cols per block (4 waves x 8 nodes, thread owns
// 8 cols). Nodes are bbox-sorted: thread run-merges its 8 nodes by bbox id,
// then one atomicMax per (bbox, col). relu >= 0 and pooled pre-zeroed, so
// uint bit-pattern max == float max. No padding waste, W_f read 5x less.
__global__ __launch_bounds__(256) void k_pool_gemm(
    const float* __restrict__ feats, const int* __restrict__ bbox,
    const float* __restrict__ Wf, const float* __restrict__ bf,
    float* __restrict__ pooled) {
  const int t = threadIdx.x, lane = t & 63, wv = t >> 6;
  const int nbase = blockIdx.x * 32 + wv * 8;
  const int col0 = blockIdx.y * 512 + lane * 8;
  float acc[8][8];
#pragma unroll
  for (int u = 0; u < 8; ++u)
#pragma unroll
    for (int i = 0; i < 8; ++i) acc[u][i] = 0.f;
  const int xrow = min(nbase + (lane >> 3), NN - 1);
  const int xk = lane & 7;
  for (int k0 = 0; k0 < FUS; k0 += 8) {
    const float xv = feats[(size_t)xrow * FUS + k0 + xk];
#pragma unroll
    for (int j = 0; j < 8; ++j) {
      const float4 w0 = *(const float4*)(Wf + (size_t)(k0 + j) * 1024 + col0);
      const float4 w1 = *(const float4*)(Wf + (size_t)(k0 + j) * 1024 + col0 + 4);
#pragma unroll
      for (int u = 0; u < 8; ++u) {
        const float xs = __shfl(xv, u * 8 + j, 64);
        acc[u][0] += xs * w0.x; acc[u][1] += xs * w0.y;
        acc[u][2] += xs * w0.z; acc[u][3] += xs * w0.w;
        acc[u][4] += xs * w1.x; acc[u][5] += xs * w1.y;
        acc[u][6] += xs * w1.z; acc[u][7] += xs * w1.w;
      }
    }
  }
  // epilogue: bias + relu, run-merge by bbox id (ascending), atomicMax
  float b8[8];
  *(float4*)&b8[0] = *(const float4*)(bf + col0);
  *(float4*)&b8[4] = *(const float4*)(bf + col0 + 4);
  int curb = -1;
  float m[8];
#pragma unroll
  for (int i = 0; i < 8; ++i) m[i] = 0.f;
#pragma unroll
  for (int u = 0; u < 8; ++u) {
    const int node = nbase + u;
    if (node < NN) {                      // wave-uniform guard
      const int bid = bbox[node];
      float v[8];
#pragma unroll
      for (int i = 0; i < 8; ++i) v[i] = fmaxf(acc[u][i] + b8[i], 0.f);
      if (bid != curb) {
        if (curb >= 0) {
#pragma unroll
          for (int i = 0; i < 8; ++i)
            atomicMax((unsigned int*)(pooled + (size_t)curb * 1408 + col0 + i),
                      __float_as_uint(m[i]));
        }
        curb = bid;
#pragma unroll
        for (int i = 0; i < 8; ++i) m[i] = v[i];
      } else {
#pragma unroll
        for (int i = 0; i < 8; ++i) m[i] = fmaxf(m[i], v[i]);
      }
    }
  }
  if (curb >= 0) {
#pragma unroll
    for (int i = 0; i < 8; ++i)
      atomicMax((unsigned int*)(pooled + (size_t)curb * 1408 + col0 + i),
                __float_as_uint(m[i]));
  }
}

// ---------- raw-feats bbox max + sfeats bbox mean ----------
__global__ __launch_bounds__(256) void k_poolraw(
    const float* __restrict__ feats, const float* __restrict__ sfeats,
    const int* __restrict__ seg, float* __restrict__ pooled,
    float* __restrict__ sb) {
  const int b = blockIdx.x, t = threadIdx.x;
  if (t >= 192) return;
  const int c2 = t * 2;
  const int n0 = __builtin_amdgcn_readfirstlane(seg[b]);
  const int n1 = __builtin_amdgcn_readfirstlane(seg[b + 1]);
  float2 fmx = {0.f, 0.f}, ss = {0.f, 0.f};
  for (int n = n0; n < n1; ++n) {
    const float2 f2 = *(const float2*)(feats + (size_t)n * FUS + c2);
    fmx.x = fmaxf(fmx.x, f2.x); fmx.y = fmaxf(fmx.y, f2.y);
    const float2 s2 = *(const float2*)(sfeats + (size_t)n * FUS + c2);
    ss.x += s2.x; ss.y += s2.y;
  }
  *(float2*)(pooled + (size_t)b * 1408 + 1024 + c2) = fmx;
  const float inv = 1.f / fmaxf((float)(n1 - n0), 1.f);
  float2 o = {ss.x * inv, ss.y * inv};
  *(float2*)(sb + (size_t)b * FUS + c2) = o;
}

// ---------- fusion_super = relu(sb @ Wfs + bfs) ----------
__global__ __launch_bounds__(256) void k_fusion_super(
    const float* __restrict__ sb, const float* __restrict__ Wfs,
    const float* __restrict__ bfs, float* __restrict__ fs) {
  const int r0 = blockIdx.x * 8, t = threadIdx.x;
  float acc[8][4];
#pragma unroll
  for (int u = 0; u < 8; ++u)
    acc[u][0] = acc[u][1] = acc[u][2] = acc[u][3] = 0.f;
  for (int k = 0; k < FUS; ++k) {
    const float4 w = *(const float4*)(Wfs + (size_t)k * 1024 + t * 4);
#pragma unroll
    for (int u = 0; u < 8; ++u) {
      float x = sb[(size_t)(r0 + u) * FUS + k];
      acc[u][0] += x * w.x; acc[u][1] += x * w.y;
      acc[u][2] += x * w.z; acc[u][3] += x * w.w;
    }
  }
  const float4 b4 = *(const float4*)(bfs + t * 4);
#pragma unroll
  for (int u = 0; u < 8; ++u) {
    float4 o = {fmaxf(acc[u][0] + b4.x, 0.f), fmaxf(acc[u][1] + b4.y, 0.f),
                fmaxf(acc[u][2] + b4.z, 0.f), fmaxf(acc[u][3] + b4.w, 0.f)};
    *(float4*)(fs + (size_t)(r0 + u) * 1024 + t * 4) = o;
  }
}

// ---------- h1 = relu(concat(pooled, fs, sb) @ W1 + b1), column-split ----------
__global__ __launch_bounds__(256) void k_mlp1(
    const float* __restrict__ pooled, const float* __restrict__ fs,
    const float* __restrict__ sb, const float* __restrict__ W1,
    const float* __restrict__ b1, float* __restrict__ h1) {
  const int r0 = blockIdx.x * 8;
  const int col = blockIdx.y * 256 + threadIdx.x;
  float acc[8];
#pragma unroll
  for (int u = 0; u < 8; ++u) acc[u] = 0.f;
  for (int k = 0; k < 1408; ++k) {
    float w = W1[(size_t)k * 512 + col];
#pragma unroll
    for (int u = 0; u < 8; ++u) acc[u] += pooled[(size_t)(r0 + u) * 1408 + k] * w;
  }
  for (int k = 0; k < 1024; ++k) {
    float w = W1[(size_t)(1408 + k) * 512 + col];
#pragma unroll
    for (int u = 0; u < 8; ++u) acc[u] += fs[(size_t)(r0 + u) * 1024 + k] * w;
  }
  for (int k = 0; k < FUS; ++k) {
    float w = W1[(size_t)(2432 + k) * 512 + col];
#pragma unroll
    for (int u = 0; u < 8; ++u) acc[u] += sb[(size_t)(r0 + u) * FUS + k] * w;
  }
  float bv = b1[col];
#pragma unroll
  for (int u = 0; u < 8; ++u)
    h1[(size_t)(r0 + u) * 512 + col] = fmaxf(acc[u] + bv, 0.f);
}

// ---------- h2 = relu(h1 @ W2 + b2) ----------
__global__ __launch_bounds__(256) void k_mlp2(
    const float* __restrict__ h1, const float* __restrict__ W2,
    const float* __restrict__ b2, float* __restrict__ h2) {
  const int r0 = blockIdx.x * 8, t = threadIdx.x;
  float acc[8];
#pragma unroll
  for (int u = 0; u < 8; ++u) acc[u] = 0.f;
  for (int k = 0; k < 512; ++k) {
    float w = W2[(size_t)k * 256 + t];
#pragma unroll
    for (int u = 0; u < 8; ++u) acc[u] += h1[(size_t)(r0 + u) * 512 + k] * w;
  }
  float bv = b2[t];
#pragma unroll
  for (int u = 0; u < 8; ++u)
    h2[(size_t)(r0 + u) * 256 + t] = fmaxf(acc[u] + bv, 0.f);
}

// ---------- logits = h2 @ W3 + b3 ----------
__global__ __launch_bounds__(256) void k_mlp3(
    const float* __restrict__ h2, const float* __restrict__ W3,
    const float* __restrict__ b3, float* __restrict__ out) {
  const int r0 = blockIdx.x * 8, t = threadIdx.x;
  const int u = t >> 5, oc = t & 31;
  const float* x = h2 + (size_t)(r0 + u) * 256;
  float acc = 0.f;
  for (int k = 0; k < 256; ++k) acc += x[k] * W3[(size_t)k * 32 + oc];
  out[(size_t)(r0 + u) * 32 + oc] = acc + b3[oc];
}

extern "C" void kernel_launch(void* const* d_in, const int* in_sizes, int n_in,
                              void* d_out, int out_size, void* d_ws, size_t ws_size,
                              hipStream_t stream) {
  const float* x     = (const float*)d_in[0];
  const float* eattr = (const float*)d_in[1];
  const float* W_h   = (const float*)d_in[2];
  const float* b_h   = (const float*)d_in[3];
  const float* Ws_h  = (const float*)d_in[4];
  const float* bs_h  = (const float*)d_in[5];
  const float* Wb    = (const float*)d_in[6];
  const float* bb    = (const float*)d_in[7];
  const float* Wbs   = (const float*)d_in[8];
  const float* bbs   = (const float*)d_in[9];
  const float* W_f   = (const float*)d_in[10];
  const float* b_f   = (const float*)d_in[11];
  const float* W_fs  = (const float*)d_in[12];
  const float* b_fs  = (const float*)d_in[13];
  const float* W1    = (const float*)d_in[14];
  const float* b1    = (const float*)d_in[15];
  const float* W2    = (const float*)d_in[16];
  const float* b2    = (const float*)d_in[17];
  const float* W3    = (const float*)d_in[18];
  const float* b3    = (const float*)d_in[19];
  const int*   edge  = (const int*)d_in[20];
  const int*   bbox  = (const int*)d_in[21];
  float* out = (float*)d_out;

  // ---- workspace layout (~209 MB) ----
  float* p = (float*)d_ws;
  float* feats  = p; p += (size_t)NN * FUS;
  float* sfeats = p; p += (size_t)NN * FUS;
  float* P      = p; p += (size_t)NN * CH;
  float* Q      = p; p += (size_t)NN * CH;
  float* sb     = P;                         // overlap: dead after convs
  float* fsup   = P + (size_t)NB * FUS;
  float* h1     = fsup + (size_t)NB * 1024;
  float* h2     = h1 + (size_t)NB * 512;
  float* pooled = Q;
  int* eid_arr = (int*)p;
  int* row_ptr = eid_arr + NE;
  int* deg     = row_ptr + NN + 1;
  int* cursor  = deg + NN;
  int* seg     = cursor + NN;

  hipMemsetAsync(deg, 0, 2 * NN * sizeof(int), stream);  // deg + cursor

  // ---- CSR build + bbox segments ----
  k_deg<<<(NE + 255) / 256, 256, 0, stream>>>(edge, deg);
  k_scan<<<1, 1024, 0, stream>>>(deg, row_ptr);
  k_fill<<<(NE + 255) / 256, 256, 0, stream>>>(edge, row_ptr, cursor, eid_arr);
  k_segstart<<<(NN + 255) / 256, 256, 0, stream>>>(bbox, seg);

  const int npq_grid = (NN + 31) / 32;

  // ---- conv 0 (head): both streams read x (K=8) ----
  k_node_pq<<<npq_grid, 256, 0, stream>>>(x, INCH, INCH, W_h, b_h, P, Q);
  k_conv<0><<<NN / 4, 256, 0, stream>>>(row_ptr, eid_arr, edge, eattr, P, Q,
                                        W_h + 2 * INCH * CH, feats, 0, -1);
  k_node_pq<<<npq_grid, 256, 0, stream>>>(x, INCH, INCH, Ws_h, bs_h, P, Q);
  k_conv<1><<<NN / 4, 256, 0, stream>>>(row_ptr, eid_arr, edge, eattr, P, Q,
                                        Ws_h + 2 * INCH * CH, sfeats, 0, -1);

  // ---- residual blocks (K=128) ----
  for (int i = 0; i < 2; ++i) {
    const float* Wi  = Wb  + (size_t)i * 262 * CH;
    const float* bi  = bb  + (size_t)i * CH;
    const float* Wsi = Wbs + (size_t)i * 262 * CH;
    const float* bsi = bbs + (size_t)i * CH;
    k_node_pq<<<npq_grid, 256, 0, stream>>>(feats + i * CH, FUS, CH, Wi, bi, P, Q);
    k_conv<0><<<NN / 4, 256, 0, stream>>>(row_ptr, eid_arr, edge, eattr, P, Q,
                                          Wi + 2 * CH * CH, feats, i + 1, i);
    k_node_pq<<<npq_grid, 256, 0, stream>>>(sfeats + i * CH, FUS, CH, Wsi, bsi, P, Q);
    k_conv<1><<<NN / 4, 256, 0, stream>>>(row_ptr, eid_arr, edge, eattr, P, Q,
                                          Wsi + 2 * CH * CH, sfeats, i + 1, i);
  }

  // ---- pooling + MLP head (Q dead -> becomes pooled; zero for atomicMax) ----
  hipMemsetAsync(pooled, 0, (size_t)NB * 1408 * sizeof(float), stream);
  k_pool_gemm<<<dim3((NN + 31) / 32, 2), 256, 0, stream>>>(feats, bbox, W_f, b_f,
                                                           pooled);
  k_poolraw<<<NB, 256, 0, stream>>>(feats, sfeats, seg, pooled, sb);
  k_fusion_super<<<NB / 8, 256, 0, stream>>>(sb, W_fs, b_fs, fsup);
  k_mlp1<<<dim3(NB / 8, 2), 256, 0, stream>>>(pooled, fsup, sb, W1, b1, h1);
  k_mlp2<<<NB / 8, 256, 0, stream>>>(h1, W2, b2, h2);
  k_mlp3<<<NB / 8, 256, 0, stream>>>(h2, W3, b3, out);
}